// Round 9
// baseline (344.093 us; speedup 1.0000x reference)
//
#include <hip/hip_runtime.h>

// Problem constants (fixed by the reference)
#define NN 50000
#define NE 800000
#define ND 16
#define ED 16
#define H  128
#define OD 4
#define SCAN_T 512
#define KPK 288     // A cols: 128 h | 128 hagg | 16 ea_agg | deg | 1 | pad to 288
#define LDAK 296    // LDS row stride (shorts)

typedef __bf16 bf16;
typedef __attribute__((ext_vector_type(8))) __bf16 bf16x8;
typedef __attribute__((ext_vector_type(4))) float f32x4;
typedef __attribute__((ext_vector_type(4))) float fvec4;   // clang vector for nt-load

static __device__ __forceinline__ float bf2f(unsigned short u) {
  return __builtin_bit_cast(float, (unsigned int)u << 16);
}
static __device__ __forceinline__ unsigned short f2bfu(float f) {
  return __builtin_bit_cast(unsigned short, (bf16)f);
}
static __device__ __forceinline__ unsigned int pk2(float a, float b) {
  return (unsigned int)f2bfu(a) | ((unsigned int)f2bfu(b) << 16);
}

// ---------------------------------------------------------------------------
// CSR build
// ---------------------------------------------------------------------------
__global__ __launch_bounds__(256) void zero_kernel(int* __restrict__ deg,
                                                   int* __restrict__ cursor) {
  int i = blockIdx.x * 256 + threadIdx.x;
  if (i < NN) { deg[i] = 0; cursor[i] = 0; }
}

__global__ __launch_bounds__(256) void degcount_kernel(
    const int* __restrict__ ei, int* __restrict__ deg) {
  int e0 = (blockIdx.x * 256 + threadIdx.x) * 4;
  if (e0 >= NE) return;   // NE % 4 == 0
  int4 d4 = *(const int4*)&ei[NE + e0];
  atomicAdd(&deg[d4.x], 1);
  atomicAdd(&deg[d4.y], 1);
  atomicAdd(&deg[d4.z], 1);
  atomicAdd(&deg[d4.w], 1);
}

__global__ __launch_bounds__(SCAN_T) void scan_part_kernel(
    const int* __restrict__ deg, int* __restrict__ offsets,
    int* __restrict__ tops) {
  __shared__ int s[SCAN_T];
  int t = threadIdx.x;
  int i = blockIdx.x * SCAN_T + t;
  int v = (i < NN) ? deg[i] : 0;
  s[t] = v;
  __syncthreads();
  for (int off = 1; off < SCAN_T; off <<= 1) {
    int a = (t >= off) ? s[t - off] : 0;
    __syncthreads();
    s[t] += a;
    __syncthreads();
  }
  if (i < NN) offsets[i] = s[t] - v;
  if (t == SCAN_T - 1) tops[blockIdx.x] = s[t];
}

__global__ void scan_tops_kernel(int* __restrict__ tops, int ntiles,
                                 int* __restrict__ offsets) {
  if (threadIdx.x == 0) {
    int run = 0;
    for (int b = 0; b < ntiles; ++b) { int v = tops[b]; tops[b] = run; run += v; }
    offsets[NN] = NE;
  }
}

__global__ __launch_bounds__(256) void scan_add_kernel(
    int* __restrict__ offsets, const int* __restrict__ tops) {
  int i = blockIdx.x * 256 + threadIdx.x;
  if (i < NN) offsets[i] += tops[i / SCAN_T];
}

// ---------------------------------------------------------------------------
// fill CSR, XCD-write-partitioned (partition = (dst*8)/NN, block blockIdx%8).
// Scatters ea[e] -> ea_perm[slot] as bf16. ea rows read nontemporally (read
// exactly once) so they don't evict partially-written ea_perm lines from L2.
// ---------------------------------------------------------------------------
__global__ __launch_bounds__(256) void csr_fill_kernel(
    const int* __restrict__ ei, const int* __restrict__ offsets,
    int* __restrict__ cursor, int* __restrict__ csr_src,
    const float* __restrict__ ea, unsigned short* __restrict__ ea_perm) {
  int part = blockIdx.x & 7;
  int e0 = (blockIdx.x >> 3) * 1024 + threadIdx.x * 4;
  if (e0 >= NE) return;
  int4 s4 = *(const int4*)&ei[e0];
  int4 d4 = *(const int4*)&ei[NE + e0];
#pragma unroll
  for (int j = 0; j < 4; ++j) {
    int dst = (&d4.x)[j];
    if ((int)(((long long)dst * 8) / NN) == part) {
      int pos = atomicAdd(&cursor[dst], 1);
      int slot = offsets[dst] + pos;
      csr_src[slot] = (&s4.x)[j];
      const fvec4* er = (const fvec4*)(ea + (size_t)(e0 + j) * ED);
      fvec4 f0 = __builtin_nontemporal_load(er + 0);
      fvec4 f1 = __builtin_nontemporal_load(er + 1);
      fvec4 f2 = __builtin_nontemporal_load(er + 2);
      fvec4 f3 = __builtin_nontemporal_load(er + 3);
      uint4 o0, o1;
      o0.x = pk2(f0.x, f0.y); o0.y = pk2(f0.z, f0.w);
      o0.z = pk2(f1.x, f1.y); o0.w = pk2(f1.z, f1.w);
      o1.x = pk2(f2.x, f2.y); o1.y = pk2(f2.z, f2.w);
      o1.z = pk2(f3.x, f3.y); o1.w = pk2(f3.z, f3.w);
      uint4* op = (uint4*)(ea_perm + (size_t)slot * 16);
      op[0] = o0; op[1] = o1;
    }
  }
}

// ---------------------------------------------------------------------------
// A[:,256:288] = [ sum_{CSR range} ea_perm (16) | deg | 1.0 | zeros ]  (bf16)
// ---------------------------------------------------------------------------
__global__ __launch_bounds__(256) void edge_static_kernel(
    const int* __restrict__ offsets, const unsigned short* __restrict__ ea_perm,
    bf16* __restrict__ A) {
  int t = threadIdx.x;
  int node = blockIdx.x * 32 + (t >> 3);
  if (node >= NN) return;
  int k = t & 7;            // cols 256+2k, 256+2k+1
  int s = offsets[node], e = offsets[node + 1];
  const unsigned int* ep = (const unsigned int*)ea_perm;
  float a0 = 0.f, a1 = 0.f;
  int p = s;
  for (; p + 2 <= e; p += 2) {
    unsigned int u0 = ep[(size_t)p * 8 + k];
    unsigned int u1 = ep[(size_t)(p + 1) * 8 + k];
    a0 += bf2f((unsigned short)(u0 & 0xffff)) + bf2f((unsigned short)(u1 & 0xffff));
    a1 += bf2f((unsigned short)(u0 >> 16)) + bf2f((unsigned short)(u1 >> 16));
  }
  if (p < e) {
    unsigned int u0 = ep[(size_t)p * 8 + k];
    a0 += bf2f((unsigned short)(u0 & 0xffff));
    a1 += bf2f((unsigned short)(u0 >> 16));
  }
  unsigned short* Au = (unsigned short*)A;
  ((unsigned int*)(Au + (size_t)node * KPK + 256))[k] = pk2(a0, a1);
  // cols 272..287: [deg, 1, 0...0]
  unsigned int v2 = (k == 0) ? pk2((float)(e - s), 1.0f) : 0u;
  ((unsigned int*)(Au + (size_t)node * KPK + 272))[k] = v2;
}

// ---------------------------------------------------------------------------
// Pack W col-major: Wp[b][c][k], c in [0,128), k in [0,288)
//   k<128   -> root_w[b][k][c]
//   k<256   -> msg_w[b][k-128][c]     (W_h)
//   k<272   -> msg_w[b][128+k-256][c] (W_e)
//   k==272  -> msg_b[b][c]
//   k==273  -> root_b[b][c]
//   else 0
// ---------------------------------------------------------------------------
__global__ __launch_bounds__(256) void pack_w_kernel(
    const float* __restrict__ msg_w, const float* __restrict__ root_w,
    const float* __restrict__ root_b, const float* __restrict__ msg_b,
    bf16* __restrict__ Wp) {
  int idx = blockIdx.x * 256 + threadIdx.x;   // 3*128*288 = 110592 exact
  int b = idx / (128 * KPK);
  int r = idx % (128 * KPK);
  int c = r / KPK, k = r % KPK;
  float v = 0.f;
  if (k < 128)       v = root_w[((size_t)b * 128 + k) * 128 + c];
  else if (k < 256)  v = msg_w[((size_t)b * 144 + (k - 128)) * 128 + c];
  else if (k < 272)  v = msg_w[((size_t)b * 144 + 128 + (k - 256)) * 128 + c];
  else if (k == 272) v = msg_b[(size_t)b * 128 + c];
  else if (k == 273) v = root_b[(size_t)b * 128 + c];
  Wp[idx] = (bf16)v;
}

// ---------------------------------------------------------------------------
// lift: A[:,0:128] = bf16(x @ lift_w + lift_b)
// ---------------------------------------------------------------------------
__global__ __launch_bounds__(256) void lift_kernel(
    const float* __restrict__ x, const float* __restrict__ lw,
    const float* __restrict__ lb, bf16* __restrict__ A) {
  int idx = blockIdx.x * 256 + threadIdx.x;   // NN*128 exact
  int n = idx >> 7, k = idx & 127;
  float acc = lb[k];
  const float* xr = x + (size_t)n * ND;
#pragma unroll
  for (int j = 0; j < ND; ++j) acc = fmaf(xr[j], lw[j * H + k], acc);
  A[(size_t)n * KPK + k] = (bf16)acc;
}

// ---------------------------------------------------------------------------
// hagg[i] = sum_{e->i} h[src[e]]  (A[:,0:128] -> A[:,128:256], f32 acc)
// 16 lanes x 16B per node; 16 nodes per 256-thread block; unroll-4
// ---------------------------------------------------------------------------
__global__ __launch_bounds__(256) void gather_h_kernel(
    const int* __restrict__ offsets, const int* __restrict__ csr_src,
    bf16* __restrict__ A) {
  int t = threadIdx.x;
  int node = blockIdx.x * 16 + (t >> 4);   // NN/16 exact
  int li = t & 15;
  int k8 = li * 8;
  int s = offsets[node], e = offsets[node + 1];
  const unsigned short* Au = (const unsigned short*)A;

  float acc[8];
#pragma unroll
  for (int j = 0; j < 8; ++j) acc[j] = 0.f;

  int p = s;
  for (; p + 4 <= e; p += 4) {
    int s0 = csr_src[p];
    int s1 = csr_src[p + 1];
    int s2 = csr_src[p + 2];
    int s3 = csr_src[p + 3];
    uint4 v0 = *(const uint4*)&Au[(size_t)s0 * KPK + k8];
    uint4 v1 = *(const uint4*)&Au[(size_t)s1 * KPK + k8];
    uint4 v2 = *(const uint4*)&Au[(size_t)s2 * KPK + k8];
    uint4 v3 = *(const uint4*)&Au[(size_t)s3 * KPK + k8];
#pragma unroll
    for (int j = 0; j < 4; ++j) {
      unsigned int w0 = (&v0.x)[j], w1 = (&v1.x)[j], w2 = (&v2.x)[j], w3 = (&v3.x)[j];
      acc[2 * j]     += (bf2f((unsigned short)(w0 & 0xffff)) + bf2f((unsigned short)(w1 & 0xffff)))
                      + (bf2f((unsigned short)(w2 & 0xffff)) + bf2f((unsigned short)(w3 & 0xffff)));
      acc[2 * j + 1] += (bf2f((unsigned short)(w0 >> 16)) + bf2f((unsigned short)(w1 >> 16)))
                      + (bf2f((unsigned short)(w2 >> 16)) + bf2f((unsigned short)(w3 >> 16)));
    }
  }
  for (; p < e; ++p) {
    int s0 = csr_src[p];
    uint4 v0 = *(const uint4*)&Au[(size_t)s0 * KPK + k8];
#pragma unroll
    for (int j = 0; j < 4; ++j) {
      unsigned int w0 = (&v0.x)[j];
      acc[2 * j]     += bf2f((unsigned short)(w0 & 0xffff));
      acc[2 * j + 1] += bf2f((unsigned short)(w0 >> 16));
    }
  }

  uint4 o;
  o.x = pk2(acc[0], acc[1]);
  o.y = pk2(acc[2], acc[3]);
  o.z = pk2(acc[4], acc[5]);
  o.w = pk2(acc[6], acc[7]);
  *(uint4*)&((unsigned short*)A)[(size_t)node * KPK + 128 + k8] = o;
}

// ---------------------------------------------------------------------------
// MFMA GEMM: h_next = act( A[64x288] @ Wp[288x128] + identity(h) )  in place.
// 4 waves x (4 row-frags x 2 col-frags); K = 288 = 9 k-steps.
// Each block reads & writes only its own 64 rows -> in-place safe.
// ---------------------------------------------------------------------------
__global__ __launch_bounds__(256, 2) void gemm_mfma_kernel(
    bf16* __restrict__ A, const bf16* __restrict__ Wp, int act) {
  __shared__ bf16 as[64 * LDAK];
  int t = threadIdx.x;
  int lane = t & 63;
  int wv = t >> 6;
  int l15 = lane & 15, g = lane >> 4;
  int c0w = wv * 32;

  bf16x8 bq[9][2];
#pragma unroll
  for (int kk = 0; kk < 9; ++kk)
#pragma unroll
    for (int ni = 0; ni < 2; ++ni)
      bq[kk][ni] = *(const bf16x8*)(Wp + (size_t)(c0w + ni * 16 + l15) * KPK + kk * 32 + g * 8);

  int m0 = blockIdx.x * 64;
  // stage 64 rows x 288 cols: 2304 16B-chunks, 9 per thread
#pragma unroll
  for (int i = 0; i < 9; ++i) {
    int idx = i * 256 + t;
    int r = idx / 36, seg = idx % 36;
    int node = m0 + r;
    float4 v = make_float4(0.f, 0.f, 0.f, 0.f);
    if (node < NN) v = *(const float4*)(A + (size_t)node * KPK + seg * 8);
    *(float4*)(as + r * LDAK + seg * 8) = v;
  }
  __syncthreads();

  f32x4 acc[4][2];
#pragma unroll
  for (int mi = 0; mi < 4; ++mi)
#pragma unroll
    for (int ni = 0; ni < 2; ++ni)
      acc[mi][ni] = (f32x4){0.f, 0.f, 0.f, 0.f};

#pragma unroll
  for (int kk = 0; kk < 9; ++kk) {
    bf16x8 af[4];
#pragma unroll
    for (int mi = 0; mi < 4; ++mi)
      af[mi] = *(const bf16x8*)(as + (mi * 16 + l15) * LDAK + kk * 32 + g * 8);
#pragma unroll
    for (int mi = 0; mi < 4; ++mi)
#pragma unroll
      for (int ni = 0; ni < 2; ++ni)
        acc[mi][ni] = __builtin_amdgcn_mfma_f32_16x16x32_bf16(
            af[mi], bq[kk][ni], acc[mi][ni], 0, 0, 0);
  }

#pragma unroll
  for (int mi = 0; mi < 4; ++mi) {
#pragma unroll
    for (int ni = 0; ni < 2; ++ni) {
#pragma unroll
      for (int i = 0; i < 4; ++i) {
        int rloc = mi * 16 + g * 4 + i;
        int row = m0 + rloc;
        int col = c0w + ni * 16 + l15;
        if (row < NN) {
          float v = acc[mi][ni][i];
          v += bf2f(__builtin_bit_cast(unsigned short, as[rloc * LDAK + col]));  // identity
          if (act) {
            float u = 0.7978845608028654f * (v + 0.044715f * v * v * v);
            v = 0.5f * v * (1.f + tanhf(u));
          }
          A[(size_t)row * KPK + col] = (bf16)v;
        }
      }
    }
  }
}

// ---------------------------------------------------------------------------
// out = h @ proj_w + proj_b
// ---------------------------------------------------------------------------
__global__ __launch_bounds__(256) void proj_kernel(
    const bf16* __restrict__ A, const float* __restrict__ pw,
    const float* __restrict__ pb, float* __restrict__ out) {
  int idx = blockIdx.x * 256 + threadIdx.x;
  if (idx >= NN * OD) return;
  int n = idx >> 2, o = idx & 3;
  float acc = pb[o];
  const unsigned short* hr = (const unsigned short*)(A + (size_t)n * KPK);
#pragma unroll
  for (int j = 0; j < H; ++j) acc = fmaf(bf2f(hr[j]), pw[j * OD + o], acc);
  out[idx] = acc;
}

extern "C" void kernel_launch(void* const* d_in, const int* in_sizes, int n_in,
                              void* d_out, int out_size, void* d_ws, size_t ws_size,
                              hipStream_t stream) {
  const float* x       = (const float*)d_in[0];
  const int*   ei      = (const int*)d_in[1];
  const float* ea      = (const float*)d_in[2];
  const float* lift_w  = (const float*)d_in[3];
  const float* lift_b  = (const float*)d_in[4];
  const float* root_w  = (const float*)d_in[5];
  const float* root_b  = (const float*)d_in[6];
  const float* msg_w   = (const float*)d_in[7];
  const float* msg_b   = (const float*)d_in[8];
  const float* proj_w  = (const float*)d_in[9];
  const float* proj_b  = (const float*)d_in[10];
  float* out = (float*)d_out;

  char* w = (char*)d_ws;
  bf16*  A      = (bf16*)w;              w += (size_t)NN * KPK * 2;      // 28.8 MB
  bf16*  Wp     = (bf16*)w;              w += (size_t)3 * 128 * KPK * 2; // 0.22 MB
  int*   csr_src = (int*)w;              w += (size_t)NE * 4;            // 3.2 MB
  unsigned short* ea_perm = (unsigned short*)w;
                                         w += (size_t)NE * 16 * 2;       // 25.6 MB
  int*   deg     = (int*)w;              w += (size_t)NN * 4;
  int*   cursor  = (int*)w;              w += (size_t)NN * 4;
  int*   offsets = (int*)w;              w += (size_t)(NN + 16) * 4;
  int*   tops    = (int*)w;

  const int ntiles = (NN + SCAN_T - 1) / SCAN_T;  // 98

  zero_kernel<<<(NN + 255) / 256, 256, 0, stream>>>(deg, cursor);
  degcount_kernel<<<(NE / 4 + 255) / 256, 256, 0, stream>>>(ei, deg);
  scan_part_kernel<<<ntiles, SCAN_T, 0, stream>>>(deg, offsets, tops);
  scan_tops_kernel<<<1, 64, 0, stream>>>(tops, ntiles, offsets);
  scan_add_kernel<<<(NN + 255) / 256, 256, 0, stream>>>(offsets, tops);
  csr_fill_kernel<<<8 * ((NE + 1023) / 1024), 256, 0, stream>>>(
      ei, offsets, cursor, csr_src, ea, ea_perm);

  edge_static_kernel<<<(NN + 31) / 32, 256, 0, stream>>>(offsets, ea_perm, A);
  pack_w_kernel<<<(3 * 128 * KPK) / 256, 256, 0, stream>>>(msg_w, root_w, root_b, msg_b, Wp);
  lift_kernel<<<(NN * H) / 256, 256, 0, stream>>>(x, lift_w, lift_b, A);

  for (int b = 0; b < 3; ++b) {
    gather_h_kernel<<<NN / 16, 256, 0, stream>>>(offsets, csr_src, A);
    gemm_mfma_kernel<<<(NN + 63) / 64, 256, 0, stream>>>(
        A, Wp + (size_t)b * 128 * KPK, b < 2 ? 1 : 0);
  }

  proj_kernel<<<(NN * OD + 255) / 256, 256, 0, stream>>>(A, proj_w, proj_b, out);
}

// Round 10
// 301.568 us; speedup vs baseline: 1.1410x; 1.1410x over previous
//
#include <hip/hip_runtime.h>

// Problem constants (fixed by the reference)
#define NN 50000
#define NE 800000
#define ND 16
#define ED 16
#define H  128
#define OD 4
#define SCAN_T 512
#define KPK 288     // GEMM K: 128 h | 128 hagg | 16 ea_agg | deg | 1 | pad
#define LDAK 296    // LDS row stride (shorts)

typedef __bf16 bf16;
typedef __attribute__((ext_vector_type(8))) __bf16 bf16x8;
typedef __attribute__((ext_vector_type(4))) float f32x4;

static __device__ __forceinline__ float bf2f(unsigned short u) {
  return __builtin_bit_cast(float, (unsigned int)u << 16);
}
static __device__ __forceinline__ unsigned short f2bfu(float f) {
  return __builtin_bit_cast(unsigned short, (bf16)f);
}
static __device__ __forceinline__ unsigned int pk2(float a, float b) {
  return (unsigned int)f2bfu(a) | ((unsigned int)f2bfu(b) << 16);
}

// ---------------------------------------------------------------------------
// CSR build
// ---------------------------------------------------------------------------
__global__ __launch_bounds__(256) void zero_kernel(int* __restrict__ deg,
                                                   int* __restrict__ cursor) {
  int i = blockIdx.x * 256 + threadIdx.x;
  if (i < NN) { deg[i] = 0; cursor[i] = 0; }
}

__global__ __launch_bounds__(256) void degcount_kernel(
    const int* __restrict__ ei, int* __restrict__ deg) {
  int e0 = (blockIdx.x * 256 + threadIdx.x) * 4;
  if (e0 >= NE) return;   // NE % 4 == 0
  int4 d4 = *(const int4*)&ei[NE + e0];
  atomicAdd(&deg[d4.x], 1);
  atomicAdd(&deg[d4.y], 1);
  atomicAdd(&deg[d4.z], 1);
  atomicAdd(&deg[d4.w], 1);
}

__global__ __launch_bounds__(SCAN_T) void scan_part_kernel(
    const int* __restrict__ deg, int* __restrict__ offsets,
    int* __restrict__ tops) {
  __shared__ int s[SCAN_T];
  int t = threadIdx.x;
  int i = blockIdx.x * SCAN_T + t;
  int v = (i < NN) ? deg[i] : 0;
  s[t] = v;
  __syncthreads();
  for (int off = 1; off < SCAN_T; off <<= 1) {
    int a = (t >= off) ? s[t - off] : 0;
    __syncthreads();
    s[t] += a;
    __syncthreads();
  }
  if (i < NN) offsets[i] = s[t] - v;
  if (t == SCAN_T - 1) tops[blockIdx.x] = s[t];
}

__global__ void scan_tops_kernel(int* __restrict__ tops, int ntiles,
                                 int* __restrict__ offsets) {
  if (threadIdx.x == 0) {
    int run = 0;
    for (int b = 0; b < ntiles; ++b) { int v = tops[b]; tops[b] = run; run += v; }
    offsets[NN] = NE;
  }
}

__global__ __launch_bounds__(256) void scan_add_kernel(
    int* __restrict__ offsets, const int* __restrict__ tops) {
  int i = blockIdx.x * 256 + threadIdx.x;
  if (i < NN) offsets[i] += tops[i / SCAN_T];
}

// ---------------------------------------------------------------------------
// fill CSR (src,eid) as one int2 store, XCD-write-partitioned:
// partition = (dst*8)/NN, block blockIdx%8 scans chunk blockIdx/8.
// ---------------------------------------------------------------------------
__global__ __launch_bounds__(256) void csr_fill_kernel(
    const int* __restrict__ ei, const int* __restrict__ offsets,
    int* __restrict__ cursor, int2* __restrict__ csr) {
  int part = blockIdx.x & 7;
  int e0 = (blockIdx.x >> 3) * 1024 + threadIdx.x * 4;
  if (e0 >= NE) return;
  int4 s4 = *(const int4*)&ei[e0];
  int4 d4 = *(const int4*)&ei[NE + e0];
#pragma unroll
  for (int j = 0; j < 4; ++j) {
    int dst = (&d4.x)[j];
    if ((int)(((long long)dst * 8) / NN) == part) {
      int pos = atomicAdd(&cursor[dst], 1);
      csr[offsets[dst] + pos] = make_int2((&s4.x)[j], e0 + j);
    }
  }
}

// ---------------------------------------------------------------------------
// stat[:,0:16] = sum_{e->i} ea[e]; stat[16]=deg; stat[17]=1; rest 0  (bf16)
// 16 lanes per node (lane k reads col k of each row -> 64B/row coalesced);
// unroll-4 for memory-level parallelism (latency-bound random row fetches)
// ---------------------------------------------------------------------------
__global__ __launch_bounds__(256) void ea_agg_kernel(
    const int* __restrict__ offsets, const int2* __restrict__ csr,
    const float* __restrict__ ea, bf16* __restrict__ stat) {
  int t = threadIdx.x;
  int node = blockIdx.x * 16 + (t >> 4);   // NN/16 exact
  int k = t & 15;
  int s = offsets[node], e = offsets[node + 1];
  const int* ci = (const int*)csr;
  float acc = 0.f;
  int p = s;
  for (; p + 4 <= e; p += 4) {
    int e0 = ci[2 * p + 1];
    int e1 = ci[2 * p + 3];
    int e2 = ci[2 * p + 5];
    int e3 = ci[2 * p + 7];
    float a0 = ea[(size_t)e0 * ED + k];
    float a1 = ea[(size_t)e1 * ED + k];
    float a2 = ea[(size_t)e2 * ED + k];
    float a3 = ea[(size_t)e3 * ED + k];
    acc += (a0 + a1) + (a2 + a3);
  }
  for (; p < e; ++p)
    acc += ea[(size_t)ci[2 * p + 1] * ED + k];
  unsigned short* S = (unsigned short*)stat;
  S[(size_t)node * 32 + k] = f2bfu(acc);
  float v2 = (k == 0) ? (float)(e - s) : (k == 1 ? 1.0f : 0.0f);
  S[(size_t)node * 32 + 16 + k] = f2bfu(v2);
}

// ---------------------------------------------------------------------------
// Pack W col-major: Wp[b][c][k], c in [0,128), k in [0,288)
//   k<128: root_w | k<256: msg_w[0:128] (W_h) | k<272: msg_w[128:144] (W_e)
//   k==272: msg_b | k==273: root_b | else 0
// ---------------------------------------------------------------------------
__global__ __launch_bounds__(256) void pack_w_kernel(
    const float* __restrict__ msg_w, const float* __restrict__ root_w,
    const float* __restrict__ root_b, const float* __restrict__ msg_b,
    bf16* __restrict__ Wp) {
  int idx = blockIdx.x * 256 + threadIdx.x;   // 3*128*288 = 110592 exact
  int b = idx / (128 * KPK);
  int r = idx % (128 * KPK);
  int c = r / KPK, k = r % KPK;
  float v = 0.f;
  if (k < 128)       v = root_w[((size_t)b * 128 + k) * 128 + c];
  else if (k < 256)  v = msg_w[((size_t)b * 144 + (k - 128)) * 128 + c];
  else if (k < 272)  v = msg_w[((size_t)b * 144 + 128 + (k - 256)) * 128 + c];
  else if (k == 272) v = msg_b[(size_t)b * 128 + c];
  else if (k == 273) v = root_b[(size_t)b * 128 + c];
  Wp[idx] = (bf16)v;
}

// ---------------------------------------------------------------------------
// lift: h = bf16(x @ lift_w + lift_b)   dense [NN][128]
// ---------------------------------------------------------------------------
__global__ __launch_bounds__(256) void lift_kernel(
    const float* __restrict__ x, const float* __restrict__ lw,
    const float* __restrict__ lb, bf16* __restrict__ h) {
  int idx = blockIdx.x * 256 + threadIdx.x;   // NN*128 exact
  int n = idx >> 7, k = idx & 127;
  float acc = lb[k];
  const float* xr = x + (size_t)n * ND;
#pragma unroll
  for (int j = 0; j < ND; ++j) acc = fmaf(xr[j], lw[j * H + k], acc);
  h[idx] = (bf16)acc;
}

// ---------------------------------------------------------------------------
// hagg[i] = sum_{e->i} h[src[e]]   (dense bf16 -> dense bf16, f32 acc)
// 16 lanes x 16B per node; 16 nodes per 256-thread block; unroll-4
// ---------------------------------------------------------------------------
__global__ __launch_bounds__(256) void gather_h_kernel(
    const int* __restrict__ offsets, const int2* __restrict__ csr,
    const bf16* __restrict__ h, bf16* __restrict__ hagg) {
  int t = threadIdx.x;
  int node = blockIdx.x * 16 + (t >> 4);   // NN/16 exact
  int li = t & 15;
  int k8 = li * 8;
  int s = offsets[node], e = offsets[node + 1];
  const int* ci = (const int*)csr;
  const unsigned short* Hu = (const unsigned short*)h;

  float acc[8];
#pragma unroll
  for (int j = 0; j < 8; ++j) acc[j] = 0.f;

  int p = s;
  for (; p + 4 <= e; p += 4) {
    int s0 = ci[2 * p];
    int s1 = ci[2 * p + 2];
    int s2 = ci[2 * p + 4];
    int s3 = ci[2 * p + 6];
    uint4 v0 = *(const uint4*)&Hu[(size_t)s0 * H + k8];
    uint4 v1 = *(const uint4*)&Hu[(size_t)s1 * H + k8];
    uint4 v2 = *(const uint4*)&Hu[(size_t)s2 * H + k8];
    uint4 v3 = *(const uint4*)&Hu[(size_t)s3 * H + k8];
#pragma unroll
    for (int j = 0; j < 4; ++j) {
      unsigned int w0 = (&v0.x)[j], w1 = (&v1.x)[j], w2 = (&v2.x)[j], w3 = (&v3.x)[j];
      acc[2 * j]     += (bf2f((unsigned short)(w0 & 0xffff)) + bf2f((unsigned short)(w1 & 0xffff)))
                      + (bf2f((unsigned short)(w2 & 0xffff)) + bf2f((unsigned short)(w3 & 0xffff)));
      acc[2 * j + 1] += (bf2f((unsigned short)(w0 >> 16)) + bf2f((unsigned short)(w1 >> 16)))
                      + (bf2f((unsigned short)(w2 >> 16)) + bf2f((unsigned short)(w3 >> 16)));
    }
  }
  for (; p < e; ++p) {
    int s0 = ci[2 * p];
    uint4 v0 = *(const uint4*)&Hu[(size_t)s0 * H + k8];
#pragma unroll
    for (int j = 0; j < 4; ++j) {
      unsigned int w0 = (&v0.x)[j];
      acc[2 * j]     += bf2f((unsigned short)(w0 & 0xffff));
      acc[2 * j + 1] += bf2f((unsigned short)(w0 >> 16));
    }
  }

  uint4 o;
  o.x = pk2(acc[0], acc[1]);
  o.y = pk2(acc[2], acc[3]);
  o.z = pk2(acc[4], acc[5]);
  o.w = pk2(acc[6], acc[7]);
  *(uint4*)&((unsigned short*)hagg)[(size_t)node * H + k8] = o;
}

// ---------------------------------------------------------------------------
// MFMA GEMM: h = act( [h|hagg|stat][64x288] @ Wp[288x128] + h )  in place.
// 4 waves x (4 row-frags x 2 col-frags); K = 288 = 9 k-steps.
// Each block reads & writes only its own 64 rows of h -> in-place safe.
// ---------------------------------------------------------------------------
__global__ __launch_bounds__(256, 2) void gemm_mfma_kernel(
    bf16* __restrict__ h, const bf16* __restrict__ hagg,
    const bf16* __restrict__ stat, const bf16* __restrict__ Wp, int act) {
  __shared__ bf16 as[64 * LDAK];
  int t = threadIdx.x;
  int lane = t & 63;
  int wv = t >> 6;
  int l15 = lane & 15, g = lane >> 4;
  int c0w = wv * 32;

  bf16x8 bq[9][2];
#pragma unroll
  for (int kk = 0; kk < 9; ++kk)
#pragma unroll
    for (int ni = 0; ni < 2; ++ni)
      bq[kk][ni] = *(const bf16x8*)(Wp + (size_t)(c0w + ni * 16 + l15) * KPK + kk * 32 + g * 8);

  int m0 = blockIdx.x * 64;
  // stage 64 rows x (h 16 | hagg 16 | stat 4) 16B-chunks = 2304, 9 per thread
#pragma unroll
  for (int i = 0; i < 9; ++i) {
    int idx = i * 256 + t;
    int r = idx / 36, seg = idx % 36;
    int node = m0 + r;
    float4 v = make_float4(0.f, 0.f, 0.f, 0.f);
    if (node < NN) {
      const bf16* src;
      if (seg < 16)      src = h    + (size_t)node * H + seg * 8;
      else if (seg < 32) src = hagg + (size_t)node * H + (seg - 16) * 8;
      else               src = stat + (size_t)node * 32 + (seg - 32) * 8;
      v = *(const float4*)src;
    }
    *(float4*)(as + r * LDAK + seg * 8) = v;
  }
  __syncthreads();

  f32x4 acc[4][2];
#pragma unroll
  for (int mi = 0; mi < 4; ++mi)
#pragma unroll
    for (int ni = 0; ni < 2; ++ni)
      acc[mi][ni] = (f32x4){0.f, 0.f, 0.f, 0.f};

#pragma unroll
  for (int kk = 0; kk < 9; ++kk) {
    bf16x8 af[4];
#pragma unroll
    for (int mi = 0; mi < 4; ++mi)
      af[mi] = *(const bf16x8*)(as + (mi * 16 + l15) * LDAK + kk * 32 + g * 8);
#pragma unroll
    for (int mi = 0; mi < 4; ++mi)
#pragma unroll
      for (int ni = 0; ni < 2; ++ni)
        acc[mi][ni] = __builtin_amdgcn_mfma_f32_16x16x32_bf16(
            af[mi], bq[kk][ni], acc[mi][ni], 0, 0, 0);
  }

#pragma unroll
  for (int mi = 0; mi < 4; ++mi) {
#pragma unroll
    for (int ni = 0; ni < 2; ++ni) {
#pragma unroll
      for (int i = 0; i < 4; ++i) {
        int rloc = mi * 16 + g * 4 + i;
        int row = m0 + rloc;
        int col = c0w + ni * 16 + l15;
        if (row < NN) {
          float v = acc[mi][ni][i];
          v += bf2f(__builtin_bit_cast(unsigned short, as[rloc * LDAK + col]));  // identity
          if (act) {
            float u = 0.7978845608028654f * (v + 0.044715f * v * v * v);
            v = 0.5f * v * (1.f + tanhf(u));
          }
          h[(size_t)row * H + col] = (bf16)v;
        }
      }
    }
  }
}

// ---------------------------------------------------------------------------
// out = h @ proj_w + proj_b
// ---------------------------------------------------------------------------
__global__ __launch_bounds__(256) void proj_kernel(
    const bf16* __restrict__ h, const float* __restrict__ pw,
    const float* __restrict__ pb, float* __restrict__ out) {
  int idx = blockIdx.x * 256 + threadIdx.x;
  if (idx >= NN * OD) return;
  int n = idx >> 2, o = idx & 3;
  float acc = pb[o];
  const unsigned short* hr = (const unsigned short*)(h + (size_t)n * H);
#pragma unroll
  for (int j = 0; j < H; ++j) acc = fmaf(bf2f(hr[j]), pw[j * OD + o], acc);
  out[idx] = acc;
}

extern "C" void kernel_launch(void* const* d_in, const int* in_sizes, int n_in,
                              void* d_out, int out_size, void* d_ws, size_t ws_size,
                              hipStream_t stream) {
  const float* x       = (const float*)d_in[0];
  const int*   ei      = (const int*)d_in[1];
  const float* ea      = (const float*)d_in[2];
  const float* lift_w  = (const float*)d_in[3];
  const float* lift_b  = (const float*)d_in[4];
  const float* root_w  = (const float*)d_in[5];
  const float* root_b  = (const float*)d_in[6];
  const float* msg_w   = (const float*)d_in[7];
  const float* msg_b   = (const float*)d_in[8];
  const float* proj_w  = (const float*)d_in[9];
  const float* proj_b  = (const float*)d_in[10];
  float* out = (float*)d_out;

  char* w = (char*)d_ws;
  bf16*  h      = (bf16*)w;              w += (size_t)NN * H * 2;        // 12.8 MB
  bf16*  hagg   = (bf16*)w;              w += (size_t)NN * H * 2;        // 12.8 MB
  bf16*  stat   = (bf16*)w;              w += (size_t)NN * 32 * 2;       //  3.2 MB
  bf16*  Wp     = (bf16*)w;              w += (size_t)3 * 128 * KPK * 2; // 0.22 MB
  int2*  csr    = (int2*)w;              w += (size_t)NE * 8;            //  6.4 MB
  int*   deg     = (int*)w;              w += (size_t)NN * 4;
  int*   cursor  = (int*)w;              w += (size_t)NN * 4;
  int*   offsets = (int*)w;              w += (size_t)(NN + 16) * 4;
  int*   tops    = (int*)w;

  const int ntiles = (NN + SCAN_T - 1) / SCAN_T;  // 98

  zero_kernel<<<(NN + 255) / 256, 256, 0, stream>>>(deg, cursor);
  degcount_kernel<<<(NE / 4 + 255) / 256, 256, 0, stream>>>(ei, deg);
  scan_part_kernel<<<ntiles, SCAN_T, 0, stream>>>(deg, offsets, tops);
  scan_tops_kernel<<<1, 64, 0, stream>>>(tops, ntiles, offsets);
  scan_add_kernel<<<(NN + 255) / 256, 256, 0, stream>>>(offsets, tops);
  csr_fill_kernel<<<8 * ((NE + 1023) / 1024), 256, 0, stream>>>(ei, offsets, cursor, csr);

  ea_agg_kernel<<<NN / 16, 256, 0, stream>>>(offsets, csr, ea, stat);
  pack_w_kernel<<<(3 * 128 * KPK) / 256, 256, 0, stream>>>(msg_w, root_w, root_b, msg_b, Wp);
  lift_kernel<<<(NN * H) / 256, 256, 0, stream>>>(x, lift_w, lift_b, h);

  for (int b = 0; b < 3; ++b) {
    gather_h_kernel<<<NN / 16, 256, 0, stream>>>(offsets, csr, h, hagg);
    gemm_mfma_kernel<<<(NN + 63) / 64, 256, 0, stream>>>(
        h, hagg, stat, Wp + (size_t)b * 128 * KPK, b < 2 ? 1 : 0);
  }

  proj_kernel<<<(NN * OD + 255) / 256, 256, 0, stream>>>(h, proj_w, proj_b, out);
}